// Round 3
// baseline (143.265 us; speedup 1.0000x reference)
//
#include <hip/hip_runtime.h>

using f32x4  = __attribute__((ext_vector_type(4))) float;
using bf16x8 = __attribute__((ext_vector_type(8))) __bf16;

// ---------- helpers ----------
__device__ __forceinline__ unsigned short f2bf(float f) {
  unsigned int u = __builtin_bit_cast(unsigned int, f);
  u = (u + 0x7FFFu + ((u >> 16) & 1u)) >> 16;   // RNE
  return (unsigned short)u;
}

__device__ __forceinline__ void g2lds16(const void* g, void* l) {
  __builtin_amdgcn_global_load_lds(
      (const __attribute__((address_space(1))) void*)g,
      (__attribute__((address_space(3))) void*)l, 16, 0, 0);
}

// ---------- combined weight prep: W cast + A repack + B repack ----------
__global__ __launch_bounds__(256) void k_prep(const float* __restrict__ W,
                                              const float* __restrict__ A,
                                              const float* __restrict__ Bexp,
                                              unsigned short* __restrict__ Wb,
                                              unsigned short* __restrict__ Ab,
                                              unsigned short* __restrict__ Bb) {
  int b = blockIdx.x;
  if (b < 2048) {                       // W: (2048,2048) f32 -> bf16, 8/thread
    int t = b * 256 + threadIdx.x;
    const float4* p = (const float4*)W;
    float4 a = p[2 * t], c = p[2 * t + 1];
    uint4 o;
    o.x = (unsigned)f2bf(a.x) | ((unsigned)f2bf(a.y) << 16);
    o.y = (unsigned)f2bf(a.z) | ((unsigned)f2bf(a.w) << 16);
    o.z = (unsigned)f2bf(c.x) | ((unsigned)f2bf(c.y) << 16);
    o.w = (unsigned)f2bf(c.z) | ((unsigned)f2bf(c.w) << 16);
    ((uint4*)Wb)[t] = o;
  } else if (b < 3072) {                // A (E,D,R) -> Ab[j=e*16+r][d]
    int t = (b - 2048) * 256 + threadIdx.x;
    int j = t >> 11, d = t & 2047;
    Ab[t] = f2bf(A[((size_t)(j >> 4) * 2048 + d) * 16 + (j & 15)]);
  } else {                              // Bexp (E,R,O) -> Bb[o][j=e*16+r]
    int t = (b - 3072) * 256 + threadIdx.x;
    int j = t >> 11, o = t & 2047;
    Bb[(size_t)o * 128 + j] = f2bf(Bexp[(size_t)(j >> 4) * 32768 + (j & 15) * 2048 + o]);
  }
}

// ---------- router (f32 exact) fused with x -> bf16 cast ----------
__global__ __launch_bounds__(256) void k_router_cast(const float* __restrict__ x,
                                                     const float* __restrict__ Wr,
                                                     unsigned short* __restrict__ xb,
                                                     float* __restrict__ wout) {
  int tok  = blockIdx.x * 4 + (threadIdx.x >> 6);
  int lane = threadIdx.x & 63;
  const float4* xr = (const float4*)(x + (size_t)tok * 2048);
  float4 xv[8];
#pragma unroll
  for (int c = 0; c < 8; c++) xv[c] = xr[c * 64 + lane];
  // cast + store this row as bf16 (8 B/lane, coalesced)
  uint2* xbr = (uint2*)(xb + (size_t)tok * 2048);
#pragma unroll
  for (int c = 0; c < 8; c++) {
    uint2 o;
    o.x = (unsigned)f2bf(xv[c].x) | ((unsigned)f2bf(xv[c].y) << 16);
    o.y = (unsigned)f2bf(xv[c].z) | ((unsigned)f2bf(xv[c].w) << 16);
    xbr[c * 64 + lane] = o;
  }
  float lg[8];
#pragma unroll
  for (int e = 0; e < 8; e++) {
    const float4* wr = (const float4*)(Wr + e * 2048);
    float p = 0.f;
#pragma unroll
    for (int c = 0; c < 8; c++) {
      float4 wv = wr[c * 64 + lane];
      p += xv[c].x * wv.x + xv[c].y * wv.y + xv[c].z * wv.z + xv[c].w * wv.w;
    }
#pragma unroll
    for (int off = 32; off; off >>= 1) p += __shfl_xor(p, off);
    lg[e] = p;
  }
  int i1 = 0;
#pragma unroll
  for (int e = 1; e < 8; e++) if (lg[e] > lg[i1]) i1 = e;
  int i2 = (i1 == 0) ? 1 : 0;
#pragma unroll
  for (int e = 0; e < 8; e++) { if (e == i1) continue; if (lg[e] > lg[i2]) i2 = e; }
  float e2 = expf(lg[i2] - lg[i1]);
  float den = 1.f + e2;
  if (lane < 8) wout[(size_t)tok * 8 + lane] =
      (lane == i1) ? (1.f / den) : ((lane == i2) ? (e2 / den) : 0.f);
}

// ---------- LoRA-down GEMM (64x128 tile, 128 blocks) ----------
__global__ __launch_bounds__(256) void k_gemm_lora(const unsigned short* __restrict__ xb,
                                                   const unsigned short* __restrict__ Ab,
                                                   const float* __restrict__ wrt,
                                                   unsigned short* __restrict__ tmat) {
  __shared__ unsigned short lsA[64 * 64];
  __shared__ unsigned short lsB[128 * 64];
  const int w = threadIdx.x >> 6, lane = threadIdx.x & 63;
  const int mBase = blockIdx.y * 64;
  const int wr = (w >> 1) * 32, wc = (w & 1) * 64;
  f32x4 z = {0.f, 0.f, 0.f, 0.f};
  f32x4 acc[2][4];
#pragma unroll
  for (int i = 0; i < 2; i++)
#pragma unroll
    for (int j = 0; j < 4; j++) acc[i][j] = z;

  for (int s = 0; s < 32; ++s) {
    int k0 = s * 64;
#pragma unroll
    for (int q = 0; q < 2; ++q) {            // A: 64 rows = 8 rowblks
      int rb = w * 2 + q;
      int r  = rb * 8 + (lane >> 3);
      int cg = (lane & 7) ^ (r & 7);
      g2lds16(xb + (size_t)(mBase + r) * 2048 + k0 + cg * 8, (char*)lsA + rb * 1024);
    }
#pragma unroll
    for (int q = 0; q < 4; ++q) {            // B: 128 rows = 16 rowblks
      int rb = w * 4 + q;
      int r  = rb * 8 + (lane >> 3);
      int cg = (lane & 7) ^ (r & 7);
      g2lds16(Ab + (size_t)r * 2048 + k0 + cg * 8, (char*)lsB + rb * 1024);
    }
    __syncthreads();
#pragma unroll
    for (int kk = 0; kk < 2; ++kk) {
      bf16x8 af[2], bv[4];
#pragma unroll
      for (int i = 0; i < 2; ++i) {
        int r = wr + i * 16 + (lane & 15);
        int c = (kk * 4 + (lane >> 4)) ^ (r & 7);
        af[i] = *(const bf16x8*)((const char*)lsA + r * 128 + c * 16);
      }
#pragma unroll
      for (int j = 0; j < 4; ++j) {
        int r = wc + j * 16 + (lane & 15);
        int c = (kk * 4 + (lane >> 4)) ^ (r & 7);
        bv[j] = *(const bf16x8*)((const char*)lsB + r * 128 + c * 16);
      }
#pragma unroll
      for (int i = 0; i < 2; ++i)
#pragma unroll
        for (int j = 0; j < 4; ++j)
          acc[i][j] = __builtin_amdgcn_mfma_f32_16x16x32_bf16(af[i], bv[j], acc[i][j], 0, 0, 0);
    }
    __syncthreads();
  }
#pragma unroll
  for (int j = 0; j < 4; ++j) {
    int jj = wc + j * 16 + (lane & 15);
    int e  = jj >> 4;
#pragma unroll
    for (int i = 0; i < 2; ++i) {
      int m0 = mBase + wr + i * 16 + (lane >> 4) * 4;
#pragma unroll
      for (int q = 0; q < 4; ++q) {
        int m = m0 + q;
        tmat[(size_t)m * 128 + jj] = f2bf(acc[i][j][q] * wrt[(size_t)m * 8 + e]);
      }
    }
  }
}

// ---------- main GEMM: 256x256, BK=64, 2 dbufs, 4 phases/K-tile (m201-style) ----------
// out = xb.Wb^T (K=2048, tiles 0..31) ++ tmat.Bb^T (K=128, tiles 32..33) + bias
#define BAR() do { __builtin_amdgcn_s_barrier(); __builtin_amdgcn_sched_barrier(0); } while (0)
#define MFMA16(IO)                                                                   \
  do {                                                                               \
    __builtin_amdgcn_s_setprio(1);                                                   \
    _Pragma("unroll")                                                                \
    for (int i_ = 0; i_ < 4; ++i_) {                                                 \
      _Pragma("unroll")                                                              \
      for (int j_ = 0; j_ < 4; ++j_)                                                 \
        acc[(IO) + i_][j_] =                                                         \
            __builtin_amdgcn_mfma_f32_16x16x32_bf16(af[i_], bv[j_], acc[(IO) + i_][j_], 0, 0, 0); \
    }                                                                                \
    __builtin_amdgcn_s_setprio(0);                                                   \
  } while (0)

__global__ __launch_bounds__(512, 2) void k_gemm_main(const unsigned short* __restrict__ xb,
                                                      const unsigned short* __restrict__ Wb,
                                                      const unsigned short* __restrict__ tm,
                                                      const unsigned short* __restrict__ Bb,
                                                      const float* __restrict__ bias,
                                                      float* __restrict__ out) {
  __shared__ unsigned short lds[65536];          // 128 KiB: A [0,64K) (2 bufs), B [64K,128K)
  char* L = (char*)lds;
  const int tid = threadIdx.x, wid = tid >> 6, lane = tid & 63;
  const int wm = wid >> 2, wn = wid & 3;         // 2M x 4N waves; wave tile 128x64
  const int bid = blockIdx.x;
  const int s = (bid & 7) * 32 + (bid >> 3);     // XCD swizzle (256 = 8*32, bijective)
  const int mBase = (s >> 3) * 256;
  const int nBase = (s & 7) * 256;
  const int rl = lane & 15, kq = lane >> 4;
  // ds_read chunk offsets (128B rows, 8 chunks, XOR row&7 swizzle -> conflict-free)
  const int c0 = ((kq) ^ (rl & 7)) * 16;         // k-slice 0
  const int c1 = ((4 + kq) ^ (rl & 7)) * 16;     // k-slice 1
  const int aRow = (wm * 128 + rl) * 128;
  const int bRow = (wn * 64 + rl) * 128;
  // staging: 512 thr x 16B covers 64 rows x 128B per op; 4 ops each for A,B
  const int sR = tid >> 3;                       // 0..63
  const int sC = ((tid & 7) ^ (sR & 7)) * 8;     // pre-swizzled source col (elems)

  auto stageTile = [&](int tau) {
    if (tau >= 34) return;
    const unsigned short *pa, *pb; int ld, k0;
    if (tau < 32) { pa = xb; pb = Wb; ld = 2048; k0 = tau * 64; }
    else          { pa = tm; pb = Bb; ld = 128;  k0 = (tau - 32) * 64; }
    const int bufo = (tau & 1) * 32768;
#pragma unroll
    for (int H = 0; H < 2; ++H)
#pragma unroll
      for (int o = 0; o < 2; ++o) {
        int r = H * 128 + o * 64 + sR;
        int dst = bufo + H * 16384 + o * 8192 + wid * 1024;
        g2lds16(pa + (size_t)(mBase + r) * ld + k0 + sC, L + dst);
        g2lds16(pb + (size_t)(nBase + r) * ld + k0 + sC, L + 65536 + dst);
      }
  };

  f32x4 z = {0.f, 0.f, 0.f, 0.f};
  f32x4 acc[8][4];
#pragma unroll
  for (int i = 0; i < 8; ++i)
#pragma unroll
    for (int j = 0; j < 4; ++j) acc[i][j] = z;

  stageTile(0);
  asm volatile("s_waitcnt vmcnt(0)" ::: "memory");
  BAR();

#pragma unroll 2
  for (int t = 0; t < 34; ++t) {
    const char* bA = L + (t & 1) * 32768;
    const char* bB = L + 65536 + (t & 1) * 32768;
    bf16x8 af[4], bv[4];
    // ---- phase 0: bv(ks0) + af(lo,ks0); stage tile t+1; MFMA acc[0..3]
#pragma unroll
    for (int j = 0; j < 4; ++j) bv[j] = *(const bf16x8*)(bB + bRow + j * 2048 + c0);
#pragma unroll
    for (int i = 0; i < 4; ++i) af[i] = *(const bf16x8*)(bA + aRow + i * 2048 + c0);
    stageTile(t + 1);
    BAR();
    MFMA16(0);
    BAR();
    // ---- phase 1: af(hi,ks0); MFMA acc[4..7] (bv held)
#pragma unroll
    for (int i = 0; i < 4; ++i) af[i] = *(const bf16x8*)(bA + aRow + (4 + i) * 2048 + c0);
    BAR();
    MFMA16(4);
    BAR();
    // ---- phase 2: bv(ks1) + af(lo,ks1); MFMA acc[0..3]
#pragma unroll
    for (int j = 0; j < 4; ++j) bv[j] = *(const bf16x8*)(bB + bRow + j * 2048 + c1);
#pragma unroll
    for (int i = 0; i < 4; ++i) af[i] = *(const bf16x8*)(bA + aRow + i * 2048 + c1);
    BAR();
    MFMA16(0);
    BAR();
    // ---- phase 3: af(hi,ks1); validate tile t+1 (ops 3 segments old); MFMA acc[4..7]
#pragma unroll
    for (int i = 0; i < 4; ++i) af[i] = *(const bf16x8*)(bA + aRow + (4 + i) * 2048 + c1);
    asm volatile("s_waitcnt vmcnt(0)" ::: "memory");
    BAR();
    MFMA16(4);
    BAR();
  }

#pragma unroll
  for (int j = 0; j < 4; ++j) {
    int o = nBase + wn * 64 + j * 16 + rl;
    float bb = bias[o];
#pragma unroll
    for (int i = 0; i < 8; ++i) {
      int m0 = mBase + wm * 128 + i * 16 + kq * 4;
#pragma unroll
      for (int q = 0; q < 4; ++q)
        out[(size_t)(m0 + q) * 2048 + o] = acc[i][j][q] + bb;
    }
  }
}

extern "C" void kernel_launch(void* const* d_in, const int* in_sizes, int n_in,
                              void* d_out, int out_size, void* d_ws, size_t ws_size,
                              hipStream_t stream) {
  const float* x    = (const float*)d_in[0];   // (4,2048,2048)
  const float* W    = (const float*)d_in[1];   // (2048,2048)
  const float* bias = (const float*)d_in[2];   // (2048)
  const float* Wr   = (const float*)d_in[3];   // (8,2048)
  const float* A    = (const float*)d_in[4];   // (8,2048,16)
  const float* Bexp = (const float*)d_in[5];   // (8,16,2048)
  float* out = (float*)d_out;

  char* ws = (char*)d_ws;
  unsigned short* xb = (unsigned short*)(ws);                 // 33,554,432 B
  unsigned short* Wb = (unsigned short*)(ws + 33554432);      //  8,388,608 B
  unsigned short* Ab = (unsigned short*)(ws + 41943040);      //    524,288 B
  unsigned short* Bb = (unsigned short*)(ws + 42467328);      //    524,288 B
  unsigned short* tm = (unsigned short*)(ws + 42991616);      //  2,097,152 B
  float*          wr = (float*)(ws + 45088768);               //    262,144 B

  (void)in_sizes; (void)n_in; (void)out_size; (void)ws_size;

  k_prep       <<<dim3(4096), 256, 0, stream>>>(W, A, Bexp, Wb, Ab, Bb);
  k_router_cast<<<dim3(2048), 256, 0, stream>>>(x, Wr, xb, wr);
  k_gemm_lora  <<<dim3(1, 128), 256, 0, stream>>>(xb, Ab, wr, tm);
  k_gemm_main  <<<dim3(256), 512, 0, stream>>>(xb, Wb, tm, Bb, bias, out);
}